// Round 9
// baseline (322.749 us; speedup 1.0000x reference)
//
#include <hip/hip_runtime.h>

#define BATCH 256
#define IMH 320
#define IMW 320
#define OUTD 314            // 320 - 7 + 1
#define NCH 9               // row chunks per sample
#define NSTRIP 3            // column strips per sample
#define RCH 36              // output rows per chunk (last chunk: 26)
#define ITERS 42            // RCH + 6 warmup

// ---------------- kernel 1: per-sample max(Y) ----------------
__global__ __launch_bounds__(256) void k_max(const float* __restrict__ Y,
                                             unsigned* __restrict__ dr) {
    int bid = blockIdx.x;
    int b = bid >> 2, part = bid & 3;
    const float4* p = (const float4*)(Y + (size_t)b * (IMH * IMW) + part * (IMH * IMW / 4));
    float m = 0.f;
    for (int i = threadIdx.x; i < (IMH * IMW / 16); i += 256) {
        float4 v = p[i];
        m = fmaxf(m, fmaxf(fmaxf(v.x, v.y), fmaxf(v.z, v.w)));
    }
    for (int off = 32; off; off >>= 1) m = fmaxf(m, __shfl_down(m, off, 64));
    __shared__ float sm[4];
    int lane = threadIdx.x & 63, wv = threadIdx.x >> 6;
    if (lane == 0) sm[wv] = m;
    __syncthreads();
    if (threadIdx.x == 0) {
        m = fmaxf(fmaxf(sm[0], sm[1]), fmaxf(sm[2], sm[3]));
        atomicMax(dr + b, __float_as_uint(m));   // Y in (0,1): uint order == float order
    }
}

// ---------------- SSIM per-pixel math (4 merged window sums) ----------------
__device__ __forceinline__ float ssim_px(float hx, float hy, float hp, float hxy,
                                         float C1, float C2) {
    const float inv = 1.f / 49.f;
    const float cn  = 49.f / 48.f;
    float ux  = hx  * inv, uy = hy * inv;
    float upp = hp  * inv;                 // mean of x^2 + y^2 window
    float uxy = hxy * inv;
    float ux2 = ux * ux, uy2 = uy * uy, uxuy = ux * uy;
    float B2 = cn * (upp - ux2 - uy2) + C2;      // vx + vy + C2
    float A2 = 2.f * cn * (uxy - uxuy) + C2;     // 2*vxy + C2
    float A1 = 2.f * uxuy + C1;
    float B1 = ux2 + uy2 + C1;
    return (A1 * A2) * __builtin_amdgcn_rcpf(B1 * B2);   // rel err ~1e-5 << 2e-2 thr
}

__device__ __forceinline__ float bperm(int addr, float v) {
    return __int_as_float(__builtin_amdgcn_ds_bpermute(addr, __float_as_int(v)));
}

// FULL = chunk is fully interior: no row guard, nout == RCH (compile-time HQ cond)
template<bool FULL>
__device__ __forceinline__ float strip_loop(const float2* __restrict__ Xp,
                                            const float2* __restrict__ Yp,
                                            int r0, int nout,
                                            int a1, int a2, int a3,
                                            bool valid, float C1, float C2) {
    float2 rx[7], ry[7];
    #pragma unroll
    for (int k = 0; k < 7; ++k) { rx[k] = make_float2(0.f, 0.f); ry[k] = make_float2(0.f, 0.f); }
    float2 sx  = make_float2(0.f, 0.f), sy  = make_float2(0.f, 0.f);
    float2 sp  = make_float2(0.f, 0.f), sxy = make_float2(0.f, 0.f);
    float part = 0.f;

    // horizontal 7-tap from 4 lane-pairs: S8 = sum of pair-sums (l..l+3);
    // h0 (cols 2c..2c+6) = S8 - y(l+3); h1 (cols 2c+1..2c+7) = S8 - x(own)
    #define HQ(q, h0, h1) {                                                    \
        float s2_ = q.x + q.y;                                                 \
        float b1_ = bperm(a1, s2_);                                            \
        float b2_ = bperm(a2, s2_);                                            \
        float b3_ = bperm(a3, s2_);                                            \
        float y3_ = bperm(a3, q.y);                                            \
        float S8_ = (s2_ + b1_) + (b2_ + b3_);                                 \
        h0 = S8_ - y3_;  h1 = S8_ - q.x; }

    #define VBODY(K, I7) {                                                     \
        const int i = (I7) + (K);                                              \
        const int r = r0 + i;                                                  \
        float2 xn = make_float2(0.f, 0.f), yn = make_float2(0.f, 0.f);         \
        if (FULL || r < IMH) { xn = Xp[r * (IMW/2)]; yn = Yp[r * (IMW/2)]; }   \
        const float2 ox = rx[K], oy = ry[K];                                   \
        sx.x  += xn.x - ox.x;              sx.y  += xn.y - ox.y;               \
        sy.x  += yn.x - oy.x;              sy.y  += yn.y - oy.y;               \
        sp.x  += (xn.x*xn.x + yn.x*yn.x) - (ox.x*ox.x + oy.x*oy.x);            \
        sp.y  += (xn.y*xn.y + yn.y*yn.y) - (ox.y*ox.y + oy.y*oy.y);            \
        sxy.x += xn.x*yn.x - ox.x*oy.x;    sxy.y += xn.y*yn.y - ox.y*oy.y;     \
        rx[K] = xn; ry[K] = yn;                                                \
        if (i >= 6 && (FULL || (i - 6) < nout)) {                              \
            float hx0,hx1,hy0,hy1,hp0,hp1,hq0,hq1;                             \
            HQ(sx,  hx0, hx1)                                                  \
            HQ(sy,  hy0, hy1)                                                  \
            HQ(sp,  hp0, hp1)                                                  \
            HQ(sxy, hq0, hq1)                                                  \
            float s0 = ssim_px(hx0, hy0, hp0, hq0, C1, C2);                    \
            float s1 = ssim_px(hx1, hy1, hp1, hq1, C1, C2);                    \
            part += valid ? (s0 + s1) : 0.f;                                   \
        }                                                                      \
    }

    for (int i7 = 0; i7 < ITERS; i7 += 7) {
        VBODY(0, i7) VBODY(1, i7) VBODY(2, i7) VBODY(3, i7)
        VBODY(4, i7) VBODY(5, i7) VBODY(6, i7)
    }
    #undef VBODY
    #undef HQ
    return part;
}

// ---------------- kernel 2: single-wave barrier-free fused SSIM ----------------
// One 64-lane wave per block; each wave owns a 128-col strip x 36-row chunk.
// Lane l -> float2 cols base+2l, base+2l+1. Vertical sliding sums in registers,
// horizontal 7-tap via ds_bpermute. No __syncthreads anywhere.
__global__ __launch_bounds__(64) void k_ssim(const float* __restrict__ X,
                                             const float* __restrict__ Y,
                                             const unsigned* __restrict__ dr,
                                             double* __restrict__ acc) {
    const int idx = blockIdx.x;
    const int b   = idx / (NCH * NSTRIP);
    const int rem = idx - b * (NCH * NSTRIP);
    const int rc  = rem / NSTRIP;
    const int s   = rem - rc * NSTRIP;
    const int l   = threadIdx.x;
    const int r0  = rc * RCH;
    const int nout = min(RCH, OUTD - r0);

    // strips: s0 -> outputs 0..121 (lanes 0..60), s1 -> 122..243 (lanes 0..60),
    // s2 -> 244..313 (lanes 26..60; lanes 0..25 & 61..63 are providers only)
    const int in_base = (s == 0) ? 0 : (s == 1 ? 122 : 192);
    const int lane_lo = (s == 2) ? 26 : 0;
    const bool valid  = (l >= lane_lo) && (l <= 60);

    const float2* Xp = (const float2*)(X + (size_t)b * (IMH * IMW)) + (in_base >> 1) + l;
    const float2* Yp = (const float2*)(Y + (size_t)b * (IMH * IMW)) + (in_base >> 1) + l;

    const int a1 = ((l + 1) & 63) << 2;
    const int a2 = ((l + 2) & 63) << 2;
    const int a3 = ((l + 3) & 63) << 2;

    const float drv = __uint_as_float(dr[b]);
    const float c1s = 0.01f * drv, c2s = 0.03f * drv;
    const float C1 = c1s * c1s, C2 = c2s * c2s;

    float part;
    if (r0 + ITERS <= IMH) {   // rc 0..7: fully interior, nout==RCH
        part = strip_loop<true >(Xp, Yp, r0, nout, a1, a2, a3, valid, C1, C2);
    } else {                   // rc 8: guarded tail
        part = strip_loop<false>(Xp, Yp, r0, nout, a1, a2, a3, valid, C1, C2);
    }

    // wave reduction, one atomic per wave
    for (int off = 32; off; off >>= 1) part += __shfl_down(part, off, 64);
    if (l == 0) atomicAdd(acc, (double)part);
}

// ---------------- kernel 3: finalize ----------------
__global__ void k_final(const double* __restrict__ acc, float* __restrict__ out) {
    const double cnt = (double)BATCH * (double)OUTD * (double)OUTD;
    out[0] = (float)(1.0 - acc[0] / cnt);
}

extern "C" void kernel_launch(void* const* d_in, const int* in_sizes, int n_in,
                              void* d_out, int out_size, void* d_ws, size_t ws_size,
                              hipStream_t stream) {
    const float* X = (const float*)d_in[0];
    const float* Y = (const float*)d_in[1];
    float* out = (float*)d_out;

    unsigned* dr = (unsigned*)d_ws;                      // 256 * 4 B
    double* acc  = (double*)((char*)d_ws + 1024);        // 8 B, aligned

    hipMemsetAsync(d_ws, 0, 2048, stream);
    k_max <<<BATCH * 4, 256, 0, stream>>>(Y, dr);
    k_ssim<<<BATCH * NCH * NSTRIP, 64, 0, stream>>>(X, Y, dr, acc);
    k_final<<<1, 1, 0, stream>>>(acc, out);
}

// Round 12
// 268.530 us; speedup vs baseline: 1.2019x; 1.2019x over previous
//
#include <hip/hip_runtime.h>

#define BATCH 256
#define IMH 320
#define IMW 320
#define OUTD 314            // 320 - 7 + 1
#define NCH 9               // row chunks per sample
#define RCH 36              // output rows per chunk (last chunk: 26)
#define ITERS 42            // RCH + 6 warmup

// ---------------- kernel 1: per-sample max(Y) ----------------
__global__ __launch_bounds__(256) void k_max(const float* __restrict__ Y,
                                             unsigned* __restrict__ dr) {
    int bid = blockIdx.x;
    int b = bid >> 2, part = bid & 3;
    const float4* p = (const float4*)(Y + (size_t)b * (IMH * IMW) + part * (IMH * IMW / 4));
    float m = 0.f;
    for (int i = threadIdx.x; i < (IMH * IMW / 16); i += 256) {
        float4 v = p[i];
        m = fmaxf(m, fmaxf(fmaxf(v.x, v.y), fmaxf(v.z, v.w)));
    }
    for (int off = 32; off; off >>= 1) m = fmaxf(m, __shfl_down(m, off, 64));
    __shared__ float sm[4];
    int lane = threadIdx.x & 63, wv = threadIdx.x >> 6;
    if (lane == 0) sm[wv] = m;
    __syncthreads();
    if (threadIdx.x == 0) {
        m = fmaxf(fmaxf(sm[0], sm[1]), fmaxf(sm[2], sm[3]));
        atomicMax(dr + b, __float_as_uint(m));   // Y in (0,1): uint order == float order
    }
}

// ---------------- SSIM per-pixel math (4 merged window sums) ----------------
__device__ __forceinline__ float ssim_px(float hx, float hy, float hp, float hxy,
                                         float C1, float C2) {
    const float inv = 1.f / 49.f;
    const float cn  = 49.f / 48.f;
    float ux  = hx  * inv, uy = hy * inv;
    float upp = hp  * inv;                 // mean of x^2 + y^2 window
    float uxy = hxy * inv;
    float ux2 = ux * ux, uy2 = uy * uy, uxuy = ux * uy;
    float B2 = cn * (upp - ux2 - uy2) + C2;      // vx + vy + C2
    float A2 = 2.f * cn * (uxy - uxuy) + C2;     // 2*vxy + C2
    float A1 = 2.f * uxuy + C1;
    float B1 = ux2 + uy2 + C1;
    return (A1 * A2) * __builtin_amdgcn_rcpf(B1 * B2);   // rel err ~1e-5 << 2e-2 thr
}

// DPP row_shl:K — lane i reads lane i+K within its 16-lane row (OOB -> 0).
// (row_shr:K reads lane i-K, per rocPRIM scan idiom; we need the +K direction.)
template<int K>
__device__ __forceinline__ float dppshl(float v) {
    return __int_as_float(__builtin_amdgcn_update_dpp(
        0, __float_as_int(v), 0x100 + K, 0xF, 0xF, true));
}

// FULL = chunk fully interior: no row guard, nout == RCH
template<bool FULL>
__device__ __forceinline__ float strip_loop(const float2* __restrict__ Xp,
                                            const float2* __restrict__ Yp,
                                            int r0, int nout,
                                            bool valid, float C1, float C2) {
    float2 rx[7], ry[7];
    #pragma unroll
    for (int k = 0; k < 7; ++k) { rx[k] = make_float2(0.f, 0.f); ry[k] = make_float2(0.f, 0.f); }
    float2 sx  = make_float2(0.f, 0.f), sy  = make_float2(0.f, 0.f);
    float2 sp  = make_float2(0.f, 0.f), sxy = make_float2(0.f, 0.f);
    float part = 0.f;

    // Horizontal 7-tap, all in VALU via DPP (no DS pipe, no lgkm waits):
    // S4 = pair-sums of lanes j..j+3 (covers group cols 2j..2j+7);
    // h0 (cols 2j..2j+6)   = S4 - y(j+3)
    // h1 (cols 2j+1..2j+7) = S4 - x(own)
    #define HQ(q, h0, h1) {                                                    \
        float s2_ = q.x + q.y;                                                 \
        float t1_ = s2_ + dppshl<1>(s2_);                                      \
        float S4_ = t1_ + dppshl<2>(t1_);                                      \
        float y3_ = dppshl<3>(q.y);                                            \
        h0 = S4_ - y3_;  h1 = S4_ - q.x; }

    #define VBODY(K, I7) {                                                     \
        const int i = (I7) + (K);                                              \
        const int r = r0 + i;                                                  \
        float2 xn = make_float2(0.f, 0.f), yn = make_float2(0.f, 0.f);         \
        if (FULL || r < IMH) { xn = Xp[r * (IMW/2)]; yn = Yp[r * (IMW/2)]; }   \
        const float2 ox = rx[K], oy = ry[K];                                   \
        sx.x  += xn.x - ox.x;              sx.y  += xn.y - ox.y;               \
        sy.x  += yn.x - oy.x;              sy.y  += yn.y - oy.y;               \
        sp.x  += (xn.x*xn.x + yn.x*yn.x) - (ox.x*ox.x + oy.x*oy.x);            \
        sp.y  += (xn.y*xn.y + yn.y*yn.y) - (ox.y*ox.y + oy.y*oy.y);            \
        sxy.x += xn.x*yn.x - ox.x*oy.x;    sxy.y += xn.y*yn.y - ox.y*oy.y;     \
        rx[K] = xn; ry[K] = yn;                                                \
        if (i >= 6 && (FULL || (i - 6) < nout)) {                              \
            float hx0,hx1,hy0,hy1,hp0,hp1,hq0,hq1;                             \
            HQ(sx,  hx0, hx1)                                                  \
            HQ(sy,  hy0, hy1)                                                  \
            HQ(sp,  hp0, hp1)                                                  \
            HQ(sxy, hq0, hq1)                                                  \
            float s0 = ssim_px(hx0, hy0, hp0, hq0, C1, C2);                    \
            float s1 = ssim_px(hx1, hy1, hp1, hq1, C1, C2);                    \
            part += valid ? (s0 + s1) : 0.f;                                   \
        }                                                                      \
    }

    for (int i7 = 0; i7 < ITERS; i7 += 7) {
        VBODY(0, i7) VBODY(1, i7) VBODY(2, i7) VBODY(3, i7)
        VBODY(4, i7) VBODY(5, i7) VBODY(6, i7)
    }
    #undef VBODY
    #undef HQ
    return part;
}

// ---------------- kernel 2: DPP-exchange fused box filter + SSIM ----------------
// 256-thr block = one (sample, row-chunk). 16-lane DPP row-group g owns input
// cols 26g..26g+31 (lane j -> float2 cols 26g+2j, +1); lanes j<=12 produce
// outputs 26g+2j, +1. Groups 0..11 -> outputs 0..311; group 12 lane 0 ->
// outputs 312,313 (seam). Groups 13..15 idle (loads clamped to dup lines).
// No DS ops and no barriers in the row loop.
__global__ __launch_bounds__(256) void k_ssim(const float* __restrict__ X,
                                              const float* __restrict__ Y,
                                              const unsigned* __restrict__ dr,
                                              double* __restrict__ acc) {
    const int idx = blockIdx.x;
    const int b   = idx / NCH;
    const int rc  = idx - b * NCH;
    const int t   = threadIdx.x;
    const int g   = t >> 4, j = t & 15;
    const int r0  = rc * RCH;
    const int nout = min(RCH, OUTD - r0);

    const bool valid = (g < 12 && j <= 12) || (g == 12 && j == 0);
    const int fidx = min(13 * g + j, (IMW / 2) - 1);   // float2 col index, clamped in-range

    const float2* Xp = (const float2*)(X + (size_t)b * (IMH * IMW)) + fidx;
    const float2* Yp = (const float2*)(Y + (size_t)b * (IMH * IMW)) + fidx;

    const float drv = __uint_as_float(dr[b]);
    const float c1s = 0.01f * drv, c2s = 0.03f * drv;
    const float C1 = c1s * c1s, C2 = c2s * c2s;

    float part;
    if (r0 + ITERS <= IMH) {   // rc 0..7: fully interior
        part = strip_loop<true >(Xp, Yp, r0, nout, valid, C1, C2);
    } else {                   // rc 8: guarded tail
        part = strip_loop<false>(Xp, Yp, r0, nout, valid, C1, C2);
    }

    // wave shuffle-reduce, then 4-wave LDS combine, one atomic per block
    for (int off = 32; off; off >>= 1) part += __shfl_down(part, off, 64);
    __shared__ float ps[4];
    const int lane = t & 63, wv = t >> 6;
    if (lane == 0) ps[wv] = part;
    __syncthreads();
    if (t == 0) atomicAdd(acc, (double)((ps[0] + ps[1]) + (ps[2] + ps[3])));
}

// ---------------- kernel 3: finalize ----------------
__global__ void k_final(const double* __restrict__ acc, float* __restrict__ out) {
    const double cnt = (double)BATCH * (double)OUTD * (double)OUTD;
    out[0] = (float)(1.0 - acc[0] / cnt);
}

extern "C" void kernel_launch(void* const* d_in, const int* in_sizes, int n_in,
                              void* d_out, int out_size, void* d_ws, size_t ws_size,
                              hipStream_t stream) {
    const float* X = (const float*)d_in[0];
    const float* Y = (const float*)d_in[1];
    float* out = (float*)d_out;

    unsigned* dr = (unsigned*)d_ws;                      // 256 * 4 B
    double* acc  = (double*)((char*)d_ws + 1024);        // 8 B, aligned

    hipMemsetAsync(d_ws, 0, 2048, stream);
    k_max <<<BATCH * 4, 256, 0, stream>>>(Y, dr);
    k_ssim<<<BATCH * NCH, 256, 0, stream>>>(X, Y, dr, acc);
    k_final<<<1, 1, 0, stream>>>(acc, out);
}